// Round 9
// baseline (104.397 us; speedup 1.0000x reference)
//
#include <hip/hip_runtime.h>

#define NB 8192
#define NK 1024
#define ND 2048
#define DELTA 4.0f

typedef __bf16 bf16x8 __attribute__((ext_vector_type(8)));
typedef float f32x4 __attribute__((ext_vector_type(4)));

#define FENCE asm volatile("" ::: "memory")
#define WAIT_VM6 asm volatile("s_waitcnt vmcnt(6)" ::: "memory")
#define WAIT_VM0 asm volatile("s_waitcnt vmcnt(0)" ::: "memory")

static __device__ __forceinline__ unsigned short f2bf(float f) {
    unsigned u = __float_as_uint(f);
    unsigned r = (u + 0x7fff + ((u >> 16) & 1)) >> 16;   // RNE
    return (unsigned short)r;
}

static __device__ __forceinline__ void async16(const void* g, void* l) {
    __builtin_amdgcn_global_load_lds(
        (const __attribute__((address_space(1))) void*)g,
        (__attribute__((address_space(3))) void*)l, 16, 0, 0);
}

// order-preserving float -> uint32 key (no NaN inputs)
static __device__ __forceinline__ unsigned skey(float s) {
    unsigned u = __float_as_uint(s);
    return (s >= 0.f) ? (u | 0x80000000u) : ~u;
}

// convert one 2048-f32 row to bf16 + squared norm (one wave)
static __device__ __forceinline__ void conv_row(const float* __restrict__ src,
                                                unsigned short* __restrict__ dst,
                                                float* __restrict__ nrm, int l) {
    const float4* row = (const float4*)src;
    ushort4* orow = (ushort4*)dst;
    float s = 0.f;
#pragma unroll
    for (int i = 0; i < 8; ++i) {
        float4 v = row[l + 64 * i];
        s += v.x * v.x + v.y * v.y + v.z * v.z + v.w * v.w;
        ushort4 h;
        h.x = f2bf(v.x); h.y = f2bf(v.y); h.z = f2bf(v.z); h.w = f2bf(v.w);
        orow[l + 64 * i] = h;
    }
#pragma unroll
    for (int m = 32; m; m >>= 1) s += __shfl_xor(s, m, 64);
    if (l == 0) *nrm = s;
}

// ---------------- fast path kernel A: fused conversions (z and e) ----------------
__global__ __launch_bounds__(256)
void prep_kernel(const float* __restrict__ z, const float* __restrict__ e,
                 unsigned short* __restrict__ zh, unsigned short* __restrict__ eh,
                 float* __restrict__ znorm, float* __restrict__ enorm) {
    const int w = threadIdx.x >> 6, l = threadIdx.x & 63;
    if (blockIdx.x < NB / 4) {
        const int b = blockIdx.x * 4 + w;
        conv_row(z + (size_t)b * ND, zh + (size_t)b * ND, znorm + b, l);
    } else {
        const int k = (blockIdx.x - NB / 4) * 4 + w;
        conv_row(e + (size_t)k * ND, eh + (size_t)k * ND, enorm + k, l);
    }
}

// ---------------- fast path kernel C: pipelined MFMA GEMM + fused chunk argmin ------
// BM=128 BN=256 BK=64, 512 threads (8 waves 2x4), 3 LDS slabs, stage 2 K-tiles ahead,
// counted vmcnt(6) at tile boundary (T3+T4), raw s_barrier (no vmcnt drain),
// XOR-swizzled LDS (chunk16 ^= row&7) via pre-swizzled global src (T2), setprio (T5).
// Epilogue identical math to round 6, extended to 4 col-groups; writes the same
// 8x(128-col) pmin/pmask layout (ballots vs full 256-tile min + DELTA — still a
// superset of the true-argmin containment proof).
__global__ __launch_bounds__(512, 1)
void gemm8_kernel(const unsigned short* __restrict__ zh,
                  const unsigned short* __restrict__ eh,
                  const float* __restrict__ enorm,
                  float* __restrict__ pmin, ulonglong2* __restrict__ pmask) {
    __shared__ __align__(16) unsigned short S[3 * 24576];   // slab: A 16KB + B 32KB
    __shared__ float rmin[128][4];
    __shared__ unsigned long long rmask[128][4];

    const int t = threadIdx.x;
    const int w = t >> 6, l = t & 63;
    const int wr = w >> 2, wc = w & 3;            // 2 x 4 waves, each 64x64 output
    const int lr = l & 15, lg = l >> 4, lx = l & 7;
    const int rowBase = blockIdx.x * 128;
    const int colBase = blockIdx.y * 256;

    f32x4 acc[4][4];
#pragma unroll
    for (int m = 0; m < 4; ++m)
#pragma unroll
        for (int n = 0; n < 4; ++n) acc[m][n] = (f32x4)(0.0f);

    // staging geometry: 512 threads, r = t>>3 in [0,64), chunk c = t&7;
    // source col-chunk = c ^ (r&7) (read-side swizzle pre-applied; LDS linear)
    const int r = t >> 3;
    const int csw = (t & 7) ^ (r & 7);
    const unsigned short* zsrc = zh + (size_t)(rowBase + r) * ND + csw * 8;
    const unsigned short* esrc = eh + (size_t)(colBase + r) * ND + csw * 8;
    const int wofs = w * 512;   // per-wave 1KB within each 8KB issue

#define STAGE_H0(K0, SL) do { \
        async16(zsrc + (K0),           &S[(SL) * 24576 +         wofs]); \
        async16(zsrc + 64 * ND + (K0), &S[(SL) * 24576 +  4096 + wofs]); \
        async16(esrc + (K0),           &S[(SL) * 24576 +  8192 + wofs]); } while (0)
#define STAGE_H1(K0, SL) do { \
        async16(esrc +  64 * ND + (K0), &S[(SL) * 24576 + 12288 + wofs]); \
        async16(esrc + 128 * ND + (K0), &S[(SL) * 24576 + 16384 + wofs]); \
        async16(esrc + 192 * ND + (K0), &S[(SL) * 24576 + 20480 + wofs]); } while (0)

    // prologue: tiles 0 and 1 in flight; wait tile 0 (6 of tile 1 remain outstanding)
    STAGE_H0(0, 0);  STAGE_H1(0, 0);
    STAGE_H0(64, 1); STAGE_H1(64, 1);
    WAIT_VM6; FENCE; __builtin_amdgcn_s_barrier(); FENCE;

    int scur = 0;
    for (int tau = 0; tau < 32; ++tau) {
        const unsigned short* SA = &S[scur * 24576];
        const unsigned short* SB = SA + 8192;
        const int spre = (scur == 0) ? 2 : scur - 1;      // (tau+2) % 3
        const int kpre = (tau + 2) * 64;

        // ---- phase A: stage half 0 of tile tau+2, compute m-half 0 ----
        if (tau < 30) STAGE_H0(kpre, spre);
        bf16x8 bfr[4][2], af[2][2];
#pragma unroll
        for (int n = 0; n < 4; ++n)
#pragma unroll
            for (int kk = 0; kk < 2; ++kk)
                bfr[n][kk] = *(const bf16x8*)&SB[(wc * 64 + n * 16 + lr) * 64
                                                 + (((lg + kk * 4) ^ lx) * 8)];
#pragma unroll
        for (int mm = 0; mm < 2; ++mm)
#pragma unroll
            for (int kk = 0; kk < 2; ++kk)
                af[mm][kk] = *(const bf16x8*)&SA[(wr * 64 + mm * 16 + lr) * 64
                                                 + (((lg + kk * 4) ^ lx) * 8)];
        __builtin_amdgcn_s_setprio(1);
#pragma unroll
        for (int mm = 0; mm < 2; ++mm)
#pragma unroll
            for (int n = 0; n < 4; ++n)
#pragma unroll
                for (int kk = 0; kk < 2; ++kk)
                    acc[mm][n] = __builtin_amdgcn_mfma_f32_16x16x32_bf16(
                        af[mm][kk], bfr[n][kk], acc[mm][n], 0, 0, 0);
        __builtin_amdgcn_s_setprio(0);

        // ---- phase B: stage half 1 of tile tau+2, compute m-half 1 ----
        if (tau < 30) STAGE_H1(kpre, spre);
#pragma unroll
        for (int mm = 0; mm < 2; ++mm)
#pragma unroll
            for (int kk = 0; kk < 2; ++kk)
                af[mm][kk] = *(const bf16x8*)&SA[(wr * 64 + (mm + 2) * 16 + lr) * 64
                                                 + (((lg + kk * 4) ^ lx) * 8)];
        __builtin_amdgcn_s_setprio(1);
#pragma unroll
        for (int mm = 0; mm < 2; ++mm)
#pragma unroll
            for (int n = 0; n < 4; ++n)
#pragma unroll
                for (int kk = 0; kk < 2; ++kk)
                    acc[mm + 2][n] = __builtin_amdgcn_mfma_f32_16x16x32_bf16(
                        af[mm][kk], bfr[n][kk], acc[mm + 2][n], 0, 0, 0);
        __builtin_amdgcn_s_setprio(0);

        // ---- tile boundary: next tile's loads done; tau+2's stay in flight ----
        if (tau < 30) { WAIT_VM6; } else { WAIT_VM0; }
        FENCE; __builtin_amdgcn_s_barrier(); FENCE;
        scur = (scur == 2) ? 0 : scur + 1;
    }
#undef STAGE_H0
#undef STAGE_H1

    // ---- epilogue: two-pass per-row min + candidate ballots (4 col-groups) ----
    float en[4];
#pragma unroll
    for (int n = 0; n < 4; ++n)
        en[n] = enorm[colBase + wc * 64 + n * 16 + lr];

#pragma unroll
    for (int m = 0; m < 4; ++m) {
#pragma unroll
        for (int j = 0; j < 4; ++j) {
            float mn = 3.0e38f;
#pragma unroll
            for (int n = 0; n < 4; ++n)
                mn = fminf(mn, en[n] - 2.0f * acc[m][n][j]);
#pragma unroll
            for (int d = 1; d < 16; d <<= 1) mn = fminf(mn, __shfl_xor(mn, d, 64));
            if (lr == 0) rmin[wr * 64 + m * 16 + lg * 4 + j][wc] = mn;
        }
    }
    __syncthreads();

#pragma unroll
    for (int m = 0; m < 4; ++m) {
#pragma unroll
        for (int j = 0; j < 4; ++j) {
            int rl = wr * 64 + m * 16 + lg * 4 + j;
            float thr = fminf(fminf(rmin[rl][0], rmin[rl][1]),
                              fminf(rmin[rl][2], rmin[rl][3])) + DELTA;
            unsigned long long seg = 0;
#pragma unroll
            for (int n = 0; n < 4; ++n) {
                unsigned long long bal = __ballot((en[n] - 2.0f * acc[m][n][j]) <= thr);
                seg |= ((bal >> (16 * lg)) & 0xFFFFull) << (n * 16);
            }
            if (lr == 0) rmask[rl][wc] = seg;
        }
    }
    __syncthreads();

    if (t < 128) {
        float m4 = fminf(fminf(rmin[t][0], rmin[t][1]), fminf(rmin[t][2], rmin[t][3]));
        size_t idx = (size_t)(rowBase + t) * 8 + (size_t)blockIdx.y * 2;
        pmin[idx] = m4;
        ulonglong2 mk0; mk0.x = rmask[t][0]; mk0.y = rmask[t][1];
        pmask[idx] = mk0;
        pmin[idx + 1] = m4;
        ulonglong2 mk1; mk1.x = rmask[t][2]; mk1.y = rmask[t][3];
        pmask[idx + 1] = mk1;
    }
}

// ---------------- fast path kernel D: merged resolve + exact rescue (round 6) -------
__global__ __launch_bounds__(256)
void resolve2_kernel(const float* __restrict__ pmin, const ulonglong2* __restrict__ pmask,
                     const float* __restrict__ z, const float* __restrict__ e,
                     const float* __restrict__ enorm, unsigned long long* __restrict__ best) {
    const int w = threadIdx.x >> 6, l = threadIdx.x & 63;
    const int b = blockIdx.x * 4 + w;

    float v = pmin[(size_t)b * 8 + (l & 7)];
#pragma unroll
    for (int d = 1; d < 8; d <<= 1) v = fminf(v, __shfl_xor(v, d, 64));
    const float thr = v + DELTA;

    unsigned long long mlo = 0, mhi = 0;
    int cnt = 0, kc = -1;
    if (l < 8) {
        float pc = pmin[(size_t)b * 8 + l];
        if (pc <= thr) {
            ulonglong2 mk = pmask[(size_t)b * 8 + l];
            mlo = mk.x; mhi = mk.y;
            cnt = __popcll(mlo) + __popcll(mhi);
            if (cnt) kc = l * 128 + (mlo ? (__ffsll((long long)mlo) - 1)
                                         : 64 + (__ffsll((long long)mhi) - 1));
        }
    }
    int tot = cnt;
#pragma unroll
    for (int d = 1; d < 8; d <<= 1) {
        tot += __shfl_xor(tot, d, 64);
        kc = max(kc, __shfl_xor(kc, d, 64));
    }
    tot = __shfl(tot, 0, 64);
    kc  = __shfl(kc, 0, 64);

    if (tot == 1) {
        if (l == 0) best[b] = ((unsigned long long)skey(v) << 32) | (unsigned)kc;
        return;
    }

    float bestv = 3.0e38f; int bestk = 0x7fffffff;
    const float4* z4 = (const float4*)(z + (size_t)b * ND);
    for (int c = 0; c < 8; ++c) {
        unsigned long long lo = __shfl(mlo, c, 64);
        unsigned long long hi = __shfl(mhi, c, 64);
        while (lo | hi) {
            int k;
            if (lo) { int bit = __ffsll((long long)lo) - 1; lo &= lo - 1; k = c * 128 + bit; }
            else    { int bit = __ffsll((long long)hi) - 1; hi &= hi - 1; k = c * 128 + 64 + bit; }
            const float4* e4 = (const float4*)(e + (size_t)k * ND);
            float dot = 0.f;
#pragma unroll
            for (int q = 0; q < 8; ++q) {
                float4 a = z4[l + 64 * q], bb = e4[l + 64 * q];
                dot += a.x * bb.x + a.y * bb.y + a.z * bb.z + a.w * bb.w;
            }
#pragma unroll
            for (int d2 = 32; d2; d2 >>= 1) dot += __shfl_xor(dot, d2, 64);
            float s = enorm[k] - 2.0f * dot;
            if (s < bestv) { bestv = s; bestk = k; }   // strict < => first occurrence
        }
    }
    if (l == 0) best[b] = ((unsigned long long)skey(bestv) << 32) | (unsigned)bestk;
}

// ---------------- fast path kernel F: loss (single block, writes — no memset) -------
__global__ __launch_bounds__(256)
void loss1_kernel(const unsigned long long* __restrict__ best,
                  const float* __restrict__ znorm, float* __restrict__ loss) {
    float s = 0.f;
    for (int b = threadIdx.x; b < NB; b += 256) {
        unsigned key = (unsigned)(best[b] >> 32);
        unsigned ub = (key & 0x80000000u) ? (key ^ 0x80000000u) : ~key;
        s += znorm[b] + __uint_as_float(ub);
    }
#pragma unroll
    for (int m = 32; m; m >>= 1) s += __shfl_xor(s, m, 64);
    __shared__ float red[4];
    int lane = threadIdx.x & 63, w = threadIdx.x >> 6;
    if (lane == 0) red[w] = s;
    __syncthreads();
    if (threadIdx.x == 0)
        loss[0] = ((red[0] + red[1]) + (red[2] + red[3])) * (12.5f / 16777216.0f);
}

// ---------------- fast path kernel G: gather e[k*(b)] -> out (decodes best) --------
__global__ __launch_bounds__(256)
void gather_kernel(const float* __restrict__ e, const unsigned long long* __restrict__ best,
                   float* __restrict__ out) {
    const int NT4 = NB * ND / 4;
    for (int f = blockIdx.x * blockDim.x + threadIdx.x; f < NT4;
         f += gridDim.x * blockDim.x) {
        int b  = f >> 9;
        int k4 = f & 511;
        int k = (int)(best[b] & 1023ull);
        ((float4*)out)[f] = *(const float4*)(e + (size_t)k * ND + (size_t)k4 * 4);
    }
}

// ---------------- fallback path (round-1, f32 VALU) ----------------
#define BK 16
#define LDS_STRIDE 20

__global__ void enorm_kernel(const float* __restrict__ e, float* __restrict__ enorm) {
    const int k = blockIdx.x;
    const int lane = threadIdx.x;
    const float4* row = (const float4*)(e + (size_t)k * ND);
    float s = 0.f;
#pragma unroll
    for (int i = 0; i < 8; ++i) {
        float4 v = row[lane + 64 * i];
        s += v.x * v.x + v.y * v.y + v.z * v.z + v.w * v.w;
    }
#pragma unroll
    for (int m = 32; m; m >>= 1) s += __shfl_xor(s, m, 64);
    if (lane == 0) enorm[k] = s;
}

__global__ __launch_bounds__(256, 2)
void argmin_kernel(const float* __restrict__ z, const float* __restrict__ e,
                   const float* __restrict__ enorm,
                   float* __restrict__ pminv, int* __restrict__ pmini) {
    __shared__ float zs[128 * LDS_STRIDE];
    __shared__ float es[128 * LDS_STRIDE];
    const int t  = threadIdx.x;
    const int tx = t & 31;
    const int ty = t >> 5;
    const int rowBase = blockIdx.x * 128;
    const int colBase = blockIdx.y * 128;

    float acc[16][4];
#pragma unroll
    for (int i = 0; i < 16; ++i)
#pragma unroll
        for (int j = 0; j < 4; ++j) acc[i][j] = 0.f;

    const int srow = t >> 2;
    const int sc4  = t & 3;

    for (int k0 = 0; k0 < ND; k0 += BK) {
#pragma unroll
        for (int q = 0; q < 2; ++q) {
            int r = srow + 64 * q;
            float4 vz = *(const float4*)(z + (size_t)(rowBase + r) * ND + k0 + sc4 * 4);
            *(float4*)(zs + r * LDS_STRIDE + sc4 * 4) = vz;
            float4 ve = *(const float4*)(e + (size_t)(colBase + r) * ND + k0 + sc4 * 4);
            *(float4*)(es + r * LDS_STRIDE + sc4 * 4) = ve;
        }
        __syncthreads();
#pragma unroll
        for (int g = 0; g < BK / 4; ++g) {
            float4 ef[4];
#pragma unroll
            for (int j = 0; j < 4; ++j)
                ef[j] = *(const float4*)(es + (tx + 32 * j) * LDS_STRIDE + g * 4);
#pragma unroll
            for (int i = 0; i < 16; ++i) {
                float4 zf = *(const float4*)(zs + (ty + 8 * i) * LDS_STRIDE + g * 4);
#pragma unroll
                for (int j = 0; j < 4; ++j) {
                    acc[i][j] += zf.x * ef[j].x;
                    acc[i][j] += zf.y * ef[j].y;
                    acc[i][j] += zf.z * ef[j].z;
                    acc[i][j] += zf.w * ef[j].w;
                }
            }
        }
        __syncthreads();
    }
#pragma unroll
    for (int i = 0; i < 16; ++i) {
        float bv = 3.0e38f; int bi = 0x7fffffff;
#pragma unroll
        for (int j = 0; j < 4; ++j) {
            int cg = colBase + tx + 32 * j;
            float s = enorm[cg] - 2.0f * acc[i][j];
            if (s < bv) { bv = s; bi = cg; }
        }
#pragma unroll
        for (int m = 16; m; m >>= 1) {
            float ov = __shfl_xor(bv, m, 64);
            int   oi = __shfl_xor(bi, m, 64);
            if (ov < bv || (ov == bv && oi < bi)) { bv = ov; bi = oi; }
        }
        if (tx == 0) {
            int r = rowBase + ty + 8 * i;
            pminv[(size_t)r * 8 + blockIdx.y] = bv;
            pmini[(size_t)r * 8 + blockIdx.y] = bi;
        }
    }
}

__global__ void final_argmin_kernel(const float* __restrict__ pminv,
                                    const int* __restrict__ pmini,
                                    int* __restrict__ ind) {
    int b = blockIdx.x * 256 + threadIdx.x;
    if (b >= NB) return;
    float bv = pminv[(size_t)b * 8];
    int   bi = pmini[(size_t)b * 8];
#pragma unroll
    for (int c = 1; c < 8; ++c) {
        float v  = pminv[(size_t)b * 8 + c];
        int   i2 = pmini[(size_t)b * 8 + c];
        if (v < bv || (v == bv && i2 < bi)) { bv = v; bi = i2; }
    }
    ind[b] = bi;
}

__global__ __launch_bounds__(256)
void gather_loss_kernel(const float* __restrict__ z, const float* __restrict__ e,
                        const int* __restrict__ ind, float* __restrict__ out,
                        float* __restrict__ loss) {
    const int NT4 = NB * ND / 4;
    float accm = 0.f;
    for (int f = blockIdx.x * blockDim.x + threadIdx.x; f < NT4;
         f += gridDim.x * blockDim.x) {
        int b  = f >> 9;
        int k4 = f & 511;
        const float4 q  = *(const float4*)(e + (size_t)ind[b] * ND + (size_t)k4 * 4);
        const float4 zz = *(const float4*)(z + (size_t)f * 4);
        *(float4*)(out + (size_t)f * 4) = q;
        float dx = q.x - zz.x, dy = q.y - zz.y, dz = q.z - zz.z, dw = q.w - zz.w;
        accm += dx * dx + dy * dy + dz * dz + dw * dw;
    }
#pragma unroll
    for (int m = 32; m; m >>= 1) accm += __shfl_xor(accm, m, 64);
    __shared__ float red[4];
    int lane = threadIdx.x & 63, w = threadIdx.x >> 6;
    if (lane == 0) red[w] = accm;
    __syncthreads();
    if (threadIdx.x == 0) {
        float s = (red[0] + red[1]) + (red[2] + red[3]);
        atomicAdd(loss, s * (12.5f / 16777216.0f));
    }
}

extern "C" void kernel_launch(void* const* d_in, const int* in_sizes, int n_in,
                              void* d_out, int out_size, void* d_ws, size_t ws_size,
                              hipStream_t stream) {
    const float* z = (const float*)d_in[0];
    const float* e = (const float*)d_in[1];
    float* out  = (float*)d_out;
    float* loss = out + (size_t)NB * ND;
    char* W = (char*)d_ws;

    const size_t OFF_ZH    = 0;                 // 32MB
    const size_t OFF_EH    = 33554432;          // 4MB
    const size_t OFF_PMIN  = 37748736;          // 256KB
    const size_t OFF_PMASK = 38010880;          // 1MB
    const size_t OFF_EN    = 39059456;          // 4KB
    const size_t OFF_ZN    = 39063552;          // 32KB
    const size_t OFF_BEST  = 39096320;          // 64KB
    const size_t NEED_FAST = 39161856 + 4096;

    if (ws_size >= NEED_FAST) {
        unsigned short* zh = (unsigned short*)(W + OFF_ZH);
        unsigned short* eh = (unsigned short*)(W + OFF_EH);
        float* pmin        = (float*)(W + OFF_PMIN);
        ulonglong2* pmask  = (ulonglong2*)(W + OFF_PMASK);
        float* enorm       = (float*)(W + OFF_EN);
        float* znorm       = (float*)(W + OFF_ZN);
        unsigned long long* best = (unsigned long long*)(W + OFF_BEST);

        hipLaunchKernelGGL(prep_kernel, dim3(NB / 4 + NK / 4), dim3(256), 0, stream,
                           z, e, zh, eh, znorm, enorm);
        hipLaunchKernelGGL(gemm8_kernel, dim3(NB / 128, NK / 256), dim3(512), 0, stream,
                           zh, eh, enorm, pmin, pmask);
        hipLaunchKernelGGL(resolve2_kernel, dim3(NB / 4), dim3(256), 0, stream,
                           pmin, pmask, z, e, enorm, best);
        hipLaunchKernelGGL(loss1_kernel, dim3(1), dim3(256), 0, stream,
                           best, znorm, loss);
        hipLaunchKernelGGL(gather_kernel, dim3(2048), dim3(256), 0, stream, e, best, out);
    } else {
        float* enorm = (float*)W;
        float* pminv = (float*)(W + 4096);
        int*   pmini = (int*)(W + 4096 + 262144);
        int*   ind   = (int*)(W + 4096 + 524288);

        hipMemsetAsync(loss, 0, sizeof(float), stream);
        hipLaunchKernelGGL(enorm_kernel, dim3(NK), dim3(64), 0, stream, e, enorm);
        hipLaunchKernelGGL(argmin_kernel, dim3(NB / 128, NK / 128), dim3(256), 0, stream,
                           z, e, enorm, pminv, pmini);
        hipLaunchKernelGGL(final_argmin_kernel, dim3(NB / 256), dim3(256), 0, stream,
                           pminv, pmini, ind);
        hipLaunchKernelGGL(gather_loss_kernel, dim3(2048), dim3(256), 0, stream,
                           z, e, ind, out, loss);
    }
}

// Round 10
// 88.455 us; speedup vs baseline: 1.1802x; 1.1802x over previous
//
#include <hip/hip_runtime.h>

#define NB 8192
#define NK 1024
#define ND 2048
#define DELTA 4.0f

typedef __bf16 bf16x8 __attribute__((ext_vector_type(8)));
typedef float f32x4 __attribute__((ext_vector_type(4)));

static __device__ __forceinline__ unsigned short f2bf(float f) {
    unsigned u = __float_as_uint(f);
    unsigned r = (u + 0x7fff + ((u >> 16) & 1)) >> 16;   // RNE
    return (unsigned short)r;
}

static __device__ __forceinline__ void async16(const void* g, void* l) {
    __builtin_amdgcn_global_load_lds(
        (const __attribute__((address_space(1))) void*)g,
        (__attribute__((address_space(3))) void*)l, 16, 0, 0);
}

// order-preserving float -> uint32 key (no NaN inputs)
static __device__ __forceinline__ unsigned skey(float s) {
    unsigned u = __float_as_uint(s);
    return (s >= 0.f) ? (u | 0x80000000u) : ~u;
}

// convert one 2048-f32 row to bf16 + squared norm (one wave)
static __device__ __forceinline__ void conv_row(const float* __restrict__ src,
                                                unsigned short* __restrict__ dst,
                                                float* __restrict__ nrm, int l) {
    const float4* row = (const float4*)src;
    ushort4* orow = (ushort4*)dst;
    float s = 0.f;
#pragma unroll
    for (int i = 0; i < 8; ++i) {
        float4 v = row[l + 64 * i];
        s += v.x * v.x + v.y * v.y + v.z * v.z + v.w * v.w;
        ushort4 h;
        h.x = f2bf(v.x); h.y = f2bf(v.y); h.z = f2bf(v.z); h.w = f2bf(v.w);
        orow[l + 64 * i] = h;
    }
#pragma unroll
    for (int m = 32; m; m >>= 1) s += __shfl_xor(s, m, 64);
    if (l == 0) *nrm = s;
}

// ---------------- fast path kernel A: fused conversions (z and e) ----------------
__global__ __launch_bounds__(256)
void prep_kernel(const float* __restrict__ z, const float* __restrict__ e,
                 unsigned short* __restrict__ zh, unsigned short* __restrict__ eh,
                 float* __restrict__ znorm, float* __restrict__ enorm) {
    const int w = threadIdx.x >> 6, l = threadIdx.x & 63;
    if (blockIdx.x < NB / 4) {
        const int b = blockIdx.x * 4 + w;
        conv_row(z + (size_t)b * ND, zh + (size_t)b * ND, znorm + b, l);
    } else {
        const int k = (blockIdx.x - NB / 4) * 4 + w;
        conv_row(e + (size_t)k * ND, eh + (size_t)k * ND, enorm + k, l);
    }
}

// ---------------- fast path kernel C: bf16 MFMA GEMM + fused chunk argmin ----------
// ROUND-6 UNIT, VERBATIM (measured twice: 43.0us, MfmaUtil 31%, 0 bank conflicts).
// 128x128 tile, BK=64, XOR-swizzled LDS (chunk16 ^= row&7), pre-swizzled gload_lds src.
// Two-pass epilogue: (1) 128-chunk row min into LDS, (2) ballots vs chunk_min + DELTA.
__global__ __launch_bounds__(256)
void coarse_gemm_kernel(const unsigned short* __restrict__ zh,
                        const unsigned short* __restrict__ eh,
                        const float* __restrict__ enorm,
                        float* __restrict__ pmin, ulonglong2* __restrict__ pmask) {
    __shared__ __align__(16) unsigned short As[128 * 64];
    __shared__ __align__(16) unsigned short Bs[128 * 64];
    __shared__ float rmin[128][2];
    __shared__ unsigned long long rmask[128][2];

    const int t = threadIdx.x;
    const int w = t >> 6, l = t & 63;
    const int wr = w & 1, wc = w >> 1;
    const int rowBase = blockIdx.x * 128;
    const int colBase = blockIdx.y * 128;

    f32x4 acc[4][4];
#pragma unroll
    for (int m = 0; m < 4; ++m)
#pragma unroll
        for (int n = 0; n < 4; ++n) acc[m][n] = (f32x4)(0.0f);

    const int r0  = t >> 3;                       // 0..31
    const int csw = (t & 7) ^ (r0 & 7);           // read-side swizzle pre-applied to src
    const size_t zsrc = (size_t)(rowBase + r0) * ND + csw * 8;
    const size_t esrc = (size_t)(colBase + r0) * ND + csw * 8;

    for (int k0 = 0; k0 < ND; k0 += 64) {
#pragma unroll
        for (int i = 0; i < 4; ++i) {
            async16(zh + zsrc + (size_t)i * 32 * ND + k0, &As[i * 2048 + w * 512]);
            async16(eh + esrc + (size_t)i * 32 * ND + k0, &Bs[i * 2048 + w * 512]);
        }
        __syncthreads();
#pragma unroll
        for (int kk = 0; kk < 2; ++kk) {
            bf16x8 af[4], bfr[4];
#pragma unroll
            for (int m = 0; m < 4; ++m) {
                int r = wr * 64 + m * 16 + (l & 15);
                int ch = ((l >> 4) + kk * 4) ^ (l & 7);
                af[m] = *(const bf16x8*)&As[r * 64 + ch * 8];
            }
#pragma unroll
            for (int n = 0; n < 4; ++n) {
                int r = wc * 64 + n * 16 + (l & 15);
                int ch = ((l >> 4) + kk * 4) ^ (l & 7);
                bfr[n] = *(const bf16x8*)&Bs[r * 64 + ch * 8];
            }
#pragma unroll
            for (int m = 0; m < 4; ++m)
#pragma unroll
                for (int n = 0; n < 4; ++n)
                    acc[m][n] = __builtin_amdgcn_mfma_f32_16x16x32_bf16(af[m], bfr[n], acc[m][n], 0, 0, 0);
        }
        __syncthreads();
    }

    float en[4];
#pragma unroll
    for (int n = 0; n < 4; ++n)
        en[n] = enorm[colBase + wc * 64 + n * 16 + (l & 15)];
    const int g = l >> 4;

    // pass 1: per-row min over this wave's 64 cols -> rmin
#pragma unroll
    for (int m = 0; m < 4; ++m) {
#pragma unroll
        for (int j = 0; j < 4; ++j) {
            float mn = 3.0e38f;
#pragma unroll
            for (int n = 0; n < 4; ++n)
                mn = fminf(mn, en[n] - 2.0f * acc[m][n][j]);
#pragma unroll
            for (int d = 1; d < 16; d <<= 1) mn = fminf(mn, __shfl_xor(mn, d, 64));
            if ((l & 15) == 0) rmin[wr * 64 + m * 16 + g * 4 + j][wc] = mn;
        }
    }
    __syncthreads();

    // pass 2: ballots against the FULL 128-col chunk min
#pragma unroll
    for (int m = 0; m < 4; ++m) {
#pragma unroll
        for (int j = 0; j < 4; ++j) {
            int rl = wr * 64 + m * 16 + g * 4 + j;
            float thr = fminf(rmin[rl][0], rmin[rl][1]) + DELTA;
            unsigned long long seg = 0;
#pragma unroll
            for (int n = 0; n < 4; ++n) {
                unsigned long long bal = __ballot((en[n] - 2.0f * acc[m][n][j]) <= thr);
                seg |= ((bal >> (16 * g)) & 0xFFFFull) << (n * 16);
            }
            if ((l & 15) == 0) rmask[rl][wc] = seg;
        }
    }
    __syncthreads();
    if (t < 128) {
        size_t idx = (size_t)(rowBase + t) * 8 + blockIdx.y;
        pmin[idx] = fminf(rmin[t][0], rmin[t][1]);
        ulonglong2 mk; mk.x = rmask[t][0]; mk.y = rmask[t][1];
        pmask[idx] = mk;
    }
}

// ---------------- fast path kernel D: merged resolve + exact rescue (round 6) -------
__global__ __launch_bounds__(256)
void resolve2_kernel(const float* __restrict__ pmin, const ulonglong2* __restrict__ pmask,
                     const float* __restrict__ z, const float* __restrict__ e,
                     const float* __restrict__ enorm, unsigned long long* __restrict__ best) {
    const int w = threadIdx.x >> 6, l = threadIdx.x & 63;
    const int b = blockIdx.x * 4 + w;

    float v = pmin[(size_t)b * 8 + (l & 7)];
#pragma unroll
    for (int d = 1; d < 8; d <<= 1) v = fminf(v, __shfl_xor(v, d, 64));
    const float thr = v + DELTA;

    unsigned long long mlo = 0, mhi = 0;
    int cnt = 0, kc = -1;
    if (l < 8) {
        float pc = pmin[(size_t)b * 8 + l];
        if (pc <= thr) {
            ulonglong2 mk = pmask[(size_t)b * 8 + l];
            mlo = mk.x; mhi = mk.y;
            cnt = __popcll(mlo) + __popcll(mhi);
            if (cnt) kc = l * 128 + (mlo ? (__ffsll((long long)mlo) - 1)
                                         : 64 + (__ffsll((long long)mhi) - 1));
        }
    }
    int tot = cnt;
#pragma unroll
    for (int d = 1; d < 8; d <<= 1) {
        tot += __shfl_xor(tot, d, 64);
        kc = max(kc, __shfl_xor(kc, d, 64));
    }
    tot = __shfl(tot, 0, 64);
    kc  = __shfl(kc, 0, 64);

    if (tot == 1) {
        if (l == 0) best[b] = ((unsigned long long)skey(v) << 32) | (unsigned)kc;
        return;
    }

    float bestv = 3.0e38f; int bestk = 0x7fffffff;
    const float4* z4 = (const float4*)(z + (size_t)b * ND);
    for (int c = 0; c < 8; ++c) {
        unsigned long long lo = __shfl(mlo, c, 64);
        unsigned long long hi = __shfl(mhi, c, 64);
        while (lo | hi) {
            int k;
            if (lo) { int bit = __ffsll((long long)lo) - 1; lo &= lo - 1; k = c * 128 + bit; }
            else    { int bit = __ffsll((long long)hi) - 1; hi &= hi - 1; k = c * 128 + 64 + bit; }
            const float4* e4 = (const float4*)(e + (size_t)k * ND);
            float dot = 0.f;
#pragma unroll
            for (int q = 0; q < 8; ++q) {
                float4 a = z4[l + 64 * q], bb = e4[l + 64 * q];
                dot += a.x * bb.x + a.y * bb.y + a.z * bb.z + a.w * bb.w;
            }
#pragma unroll
            for (int d2 = 32; d2; d2 >>= 1) dot += __shfl_xor(dot, d2, 64);
            float s = enorm[k] - 2.0f * dot;
            if (s < bestv) { bestv = s; bestk = k; }   // strict < => first occurrence
        }
    }
    if (l == 0) best[b] = ((unsigned long long)skey(bestv) << 32) | (unsigned)bestk;
}

// ---------------- fast path kernel E: gather + loss (loss in last block) ------------
// grid 2049: blocks 0..2047 stream e[k*(b)] -> out; block 2048 computes + WRITES loss.
__global__ __launch_bounds__(256)
void gather_loss2_kernel(const float* __restrict__ e,
                         const unsigned long long* __restrict__ best,
                         const float* __restrict__ znorm,
                         float* __restrict__ out, float* __restrict__ loss) {
    if (blockIdx.x == gridDim.x - 1) {
        float s = 0.f;
        for (int b = threadIdx.x; b < NB; b += 256) {
            unsigned key = (unsigned)(best[b] >> 32);
            unsigned ub = (key & 0x80000000u) ? (key ^ 0x80000000u) : ~key;
            s += znorm[b] + __uint_as_float(ub);   // ||z_b||^2 + s(k*) = ||z_b - e_k*||^2
        }
#pragma unroll
        for (int m = 32; m; m >>= 1) s += __shfl_xor(s, m, 64);
        __shared__ float red[4];
        int lane = threadIdx.x & 63, w = threadIdx.x >> 6;
        if (lane == 0) red[w] = s;
        __syncthreads();
        if (threadIdx.x == 0)
            loss[0] = ((red[0] + red[1]) + (red[2] + red[3])) * (12.5f / 16777216.0f);
        return;
    }
    const int NT4 = NB * ND / 4;
    const int nstream = (gridDim.x - 1) * blockDim.x;
    for (int f = blockIdx.x * blockDim.x + threadIdx.x; f < NT4; f += nstream) {
        int b  = f >> 9;
        int k4 = f & 511;
        int k = (int)(best[b] & 1023ull);
        ((float4*)out)[f] = *(const float4*)(e + (size_t)k * ND + (size_t)k4 * 4);
    }
}

// ---------------- fallback path (round-1, f32 VALU) ----------------
#define BK 16
#define LDS_STRIDE 20

__global__ void enorm_kernel(const float* __restrict__ e, float* __restrict__ enorm) {
    const int k = blockIdx.x;
    const int lane = threadIdx.x;
    const float4* row = (const float4*)(e + (size_t)k * ND);
    float s = 0.f;
#pragma unroll
    for (int i = 0; i < 8; ++i) {
        float4 v = row[lane + 64 * i];
        s += v.x * v.x + v.y * v.y + v.z * v.z + v.w * v.w;
    }
#pragma unroll
    for (int m = 32; m; m >>= 1) s += __shfl_xor(s, m, 64);
    if (lane == 0) enorm[k] = s;
}

__global__ __launch_bounds__(256, 2)
void argmin_kernel(const float* __restrict__ z, const float* __restrict__ e,
                   const float* __restrict__ enorm,
                   float* __restrict__ pminv, int* __restrict__ pmini) {
    __shared__ float zs[128 * LDS_STRIDE];
    __shared__ float es[128 * LDS_STRIDE];
    const int t  = threadIdx.x;
    const int tx = t & 31;
    const int ty = t >> 5;
    const int rowBase = blockIdx.x * 128;
    const int colBase = blockIdx.y * 128;

    float acc[16][4];
#pragma unroll
    for (int i = 0; i < 16; ++i)
#pragma unroll
        for (int j = 0; j < 4; ++j) acc[i][j] = 0.f;

    const int srow = t >> 2;
    const int sc4  = t & 3;

    for (int k0 = 0; k0 < ND; k0 += BK) {
#pragma unroll
        for (int q = 0; q < 2; ++q) {
            int r = srow + 64 * q;
            float4 vz = *(const float4*)(z + (size_t)(rowBase + r) * ND + k0 + sc4 * 4);
            *(float4*)(zs + r * LDS_STRIDE + sc4 * 4) = vz;
            float4 ve = *(const float4*)(e + (size_t)(colBase + r) * ND + k0 + sc4 * 4);
            *(float4*)(es + r * LDS_STRIDE + sc4 * 4) = ve;
        }
        __syncthreads();
#pragma unroll
        for (int g = 0; g < BK / 4; ++g) {
            float4 ef[4];
#pragma unroll
            for (int j = 0; j < 4; ++j)
                ef[j] = *(const float4*)(es + (tx + 32 * j) * LDS_STRIDE + g * 4);
#pragma unroll
            for (int i = 0; i < 16; ++i) {
                float4 zf = *(const float4*)(zs + (ty + 8 * i) * LDS_STRIDE + g * 4);
#pragma unroll
                for (int j = 0; j < 4; ++j) {
                    acc[i][j] += zf.x * ef[j].x;
                    acc[i][j] += zf.y * ef[j].y;
                    acc[i][j] += zf.z * ef[j].z;
                    acc[i][j] += zf.w * ef[j].w;
                }
            }
        }
        __syncthreads();
    }
#pragma unroll
    for (int i = 0; i < 16; ++i) {
        float bv = 3.0e38f; int bi = 0x7fffffff;
#pragma unroll
        for (int j = 0; j < 4; ++j) {
            int cg = colBase + tx + 32 * j;
            float s = enorm[cg] - 2.0f * acc[i][j];
            if (s < bv) { bv = s; bi = cg; }
        }
#pragma unroll
        for (int m = 16; m; m >>= 1) {
            float ov = __shfl_xor(bv, m, 64);
            int   oi = __shfl_xor(bi, m, 64);
            if (ov < bv || (ov == bv && oi < bi)) { bv = ov; bi = oi; }
        }
        if (tx == 0) {
            int r = rowBase + ty + 8 * i;
            pminv[(size_t)r * 8 + blockIdx.y] = bv;
            pmini[(size_t)r * 8 + blockIdx.y] = bi;
        }
    }
}

__global__ void final_argmin_kernel(const float* __restrict__ pminv,
                                    const int* __restrict__ pmini,
                                    int* __restrict__ ind) {
    int b = blockIdx.x * 256 + threadIdx.x;
    if (b >= NB) return;
    float bv = pminv[(size_t)b * 8];
    int   bi = pmini[(size_t)b * 8];
#pragma unroll
    for (int c = 1; c < 8; ++c) {
        float v  = pminv[(size_t)b * 8 + c];
        int   i2 = pmini[(size_t)b * 8 + c];
        if (v < bv || (v == bv && i2 < bi)) { bv = v; bi = i2; }
    }
    ind[b] = bi;
}

__global__ __launch_bounds__(256)
void gather_loss_kernel(const float* __restrict__ z, const float* __restrict__ e,
                        const int* __restrict__ ind, float* __restrict__ out,
                        float* __restrict__ loss) {
    const int NT4 = NB * ND / 4;
    float accm = 0.f;
    for (int f = blockIdx.x * blockDim.x + threadIdx.x; f < NT4;
         f += gridDim.x * blockDim.x) {
        int b  = f >> 9;
        int k4 = f & 511;
        const float4 q  = *(const float4*)(e + (size_t)ind[b] * ND + (size_t)k4 * 4);
        const float4 zz = *(const float4*)(z + (size_t)f * 4);
        *(float4*)(out + (size_t)f * 4) = q;
        float dx = q.x - zz.x, dy = q.y - zz.y, dz = q.z - zz.z, dw = q.w - zz.w;
        accm += dx * dx + dy * dy + dz * dz + dw * dw;
    }
#pragma unroll
    for (int m = 32; m; m >>= 1) accm += __shfl_xor(accm, m, 64);
    __shared__ float red[4];
    int lane = threadIdx.x & 63, w = threadIdx.x >> 6;
    if (lane == 0) red[w] = accm;
    __syncthreads();
    if (threadIdx.x == 0) {
        float s = (red[0] + red[1]) + (red[2] + red[3]);
        atomicAdd(loss, s * (12.5f / 16777216.0f));
    }
}

extern "C" void kernel_launch(void* const* d_in, const int* in_sizes, int n_in,
                              void* d_out, int out_size, void* d_ws, size_t ws_size,
                              hipStream_t stream) {
    const float* z = (const float*)d_in[0];
    const float* e = (const float*)d_in[1];
    float* out  = (float*)d_out;
    float* loss = out + (size_t)NB * ND;
    char* W = (char*)d_ws;

    const size_t OFF_ZH    = 0;                 // 32MB
    const size_t OFF_EH    = 33554432;          // 4MB
    const size_t OFF_PMIN  = 37748736;          // 256KB
    const size_t OFF_PMASK = 38010880;          // 1MB
    const size_t OFF_EN    = 39059456;          // 4KB
    const size_t OFF_ZN    = 39063552;          // 32KB
    const size_t OFF_BEST  = 39096320;          // 64KB
    const size_t NEED_FAST = 39161856 + 4096;

    if (ws_size >= NEED_FAST) {
        unsigned short* zh = (unsigned short*)(W + OFF_ZH);
        unsigned short* eh = (unsigned short*)(W + OFF_EH);
        float* pmin        = (float*)(W + OFF_PMIN);
        ulonglong2* pmask  = (ulonglong2*)(W + OFF_PMASK);
        float* enorm       = (float*)(W + OFF_EN);
        float* znorm       = (float*)(W + OFF_ZN);
        unsigned long long* best = (unsigned long long*)(W + OFF_BEST);

        hipLaunchKernelGGL(prep_kernel, dim3(NB / 4 + NK / 4), dim3(256), 0, stream,
                           z, e, zh, eh, znorm, enorm);
        hipLaunchKernelGGL(coarse_gemm_kernel, dim3(NB / 128, NK / 128), dim3(256), 0, stream,
                           zh, eh, enorm, pmin, pmask);
        hipLaunchKernelGGL(resolve2_kernel, dim3(NB / 4), dim3(256), 0, stream,
                           pmin, pmask, z, e, enorm, best);
        hipLaunchKernelGGL(gather_loss2_kernel, dim3(2049), dim3(256), 0, stream,
                           e, best, znorm, out, loss);
    } else {
        float* enorm = (float*)W;
        float* pminv = (float*)(W + 4096);
        int*   pmini = (int*)(W + 4096 + 262144);
        int*   ind   = (int*)(W + 4096 + 524288);

        hipMemsetAsync(loss, 0, sizeof(float), stream);
        hipLaunchKernelGGL(enorm_kernel, dim3(NK), dim3(64), 0, stream, e, enorm);
        hipLaunchKernelGGL(argmin_kernel, dim3(NB / 128, NK / 128), dim3(256), 0, stream,
                           z, e, enorm, pminv, pmini);
        hipLaunchKernelGGL(final_argmin_kernel, dim3(NB / 256), dim3(256), 0, stream,
                           pminv, pmini, ind);
        hipLaunchKernelGGL(gather_loss_kernel, dim3(2048), dim3(256), 0, stream,
                           z, e, ind, out, loss);
    }
}